// Round 1
// baseline (204.990 us; speedup 1.0000x reference)
//
#include <hip/hip_runtime.h>

#define BATCH 512
#define NI 1152
#define ND 8
#define NO 10
#define NE 16

constexpr int THREADS = 512;
constexpr int WAVES   = THREADS / 64;   // 8
constexpr int QUADS   = THREADS / 4;    // 128 i-rows per sweep
constexpr int ITEMS   = NI / QUADS;     // 9 (exact: 1152 = 128*9)

// One block per (o, b) pair. Each thread owns ITEMS (i, e4) cells of the
// [1152 x 16] priors slice, kept ENTIRELY in registers (9 float4 = 36 VGPR).
// Routing needs only quad shuffles (dot over E) and e4-group shuffles
// (sum over I) -> no LDS priors tile, priors computed exactly once.
__global__ __launch_bounds__(THREADS)
void caps_routing(const float* __restrict__ x,
                  const float* __restrict__ Wt,
                  float* __restrict__ out)
{
    const int o = blockIdx.x / BATCH;
    const int b = blockIdx.x % BATCH;

    __shared__ __align__(16) float red[WAVES * 16];
    __shared__ float sv[16];
    __shared__ float rs[WAVES];

    const int t    = threadIdx.x;
    const int lane = t & 63;
    const int w    = t >> 6;
    const int e4   = t & 3;     // which float4 of the 16-wide E dim
    const int iq   = t >> 2;    // i-quad id, i = iq + k*QUADS

    const float* xb = x  + (size_t)b * (NI * ND);
    const float* Wo = Wt + (size_t)o * ((size_t)NI * ND * NE);

    float4 p[ITEMS];     // register-resident priors slice
    float  lg[ITEMS];    // register-resident logits
    float4 acc = make_float4(0.f, 0.f, 0.f, 0.f);

    // ---- priors = x[b,i,:] @ W[o,i,:,:], fused with iter-0 uniform sum ----
#pragma unroll
    for (int k = 0; k < ITEMS; ++k) {
        const int i = iq + k * QUADS;
        const float4 xa = *(const float4*)(xb + (size_t)i * ND);
        const float4 xc = *(const float4*)(xb + (size_t)i * ND + 4);
        const float4* Wp = (const float4*)(Wo + (size_t)i * (ND * NE));
        float4 v = make_float4(0.f, 0.f, 0.f, 0.f);
#define DSTEP(dd, xs) { const float4 wv = Wp[(dd)*4 + e4]; \
        v.x += (xs)*wv.x; v.y += (xs)*wv.y; v.z += (xs)*wv.z; v.w += (xs)*wv.w; }
        DSTEP(0, xa.x) DSTEP(1, xa.y) DSTEP(2, xa.z) DSTEP(3, xa.w)
        DSTEP(4, xc.x) DSTEP(5, xc.y) DSTEP(6, xc.z) DSTEP(7, xc.w)
#undef DSTEP
        p[k] = v;
        acc.x += v.x; acc.y += v.y; acc.z += v.z; acc.w += v.w;
    }

    // ---- s0 = mean_i priors : reduce across quads (same e4) ----
#pragma unroll
    for (int off = 4; off <= 32; off <<= 1) {
        acc.x += __shfl_xor(acc.x, off);
        acc.y += __shfl_xor(acc.y, off);
        acc.z += __shfl_xor(acc.z, off);
        acc.w += __shfl_xor(acc.w, off);
    }
    if (lane < 4) *(float4*)&red[w * 16 + e4 * 4] = acc;   // lane==e4 here
    __syncthreads();
    if (t < 16) {
        float s = 0.f;
#pragma unroll
        for (int q = 0; q < WAVES; ++q) s += red[q * 16 + t];
        sv[t] = s * (1.0f / (float)NI);
    }
    __syncthreads();

    // ---- squash(s0) -> outv (each thread keeps its e4 slice) ----
    float4 outv;
    {
        float sq = 0.f;
#pragma unroll
        for (int e = 0; e < 16; ++e) { const float vv = sv[e]; sq += vv * vv; }
        const float scale = sqrtf(sq) / (1.0f + sq);
        outv.x = sv[e4 * 4 + 0] * scale;
        outv.y = sv[e4 * 4 + 1] * scale;
        outv.z = sv[e4 * 4 + 2] * scale;
        outv.w = sv[e4 * 4 + 3] * scale;
    }

    // ---- routing iterations 1 and 2 ----
    for (int it = 1; it < 3; ++it) {
        // pass A: logits += priors . outv ; track max for softmax
        float lmax = -1e30f;
#pragma unroll
        for (int k = 0; k < ITEMS; ++k) {
            const float4 v = p[k];
            float part = v.x * outv.x + v.y * outv.y + v.z * outv.z + v.w * outv.w;
            part += __shfl_xor(part, 1);   // quad reduce: full dot over 16 E
            part += __shfl_xor(part, 2);
            const float l = (it == 1) ? part : (lg[k] + part);
            lg[k] = l;
            lmax = fmaxf(lmax, l);
        }
#pragma unroll
        for (int off = 1; off <= 32; off <<= 1)
            lmax = fmaxf(lmax, __shfl_xor(lmax, off));
        if (lane == 0) rs[w] = lmax;
        __syncthreads();
        float m = rs[0];
#pragma unroll
        for (int q = 1; q < WAVES; ++q) m = fmaxf(m, rs[q]);

        // pass B: s = sum_i softmax(lg)_i * priors_i
        float4 pacc = make_float4(0.f, 0.f, 0.f, 0.f);
        float  lsum = 0.f;
#pragma unroll
        for (int k = 0; k < ITEMS; ++k) {
            const float wgt = __expf(lg[k] - m);
            const float4 v = p[k];
            pacc.x += wgt * v.x; pacc.y += wgt * v.y;
            pacc.z += wgt * v.z; pacc.w += wgt * v.w;
            lsum += wgt;                    // counted by all 4 quad lanes -> /4 later
        }
#pragma unroll
        for (int off = 4; off <= 32; off <<= 1) {
            pacc.x += __shfl_xor(pacc.x, off);
            pacc.y += __shfl_xor(pacc.y, off);
            pacc.z += __shfl_xor(pacc.z, off);
            pacc.w += __shfl_xor(pacc.w, off);
        }
#pragma unroll
        for (int off = 1; off <= 32; off <<= 1)
            lsum += __shfl_xor(lsum, off);
        __syncthreads();   // everyone has consumed rs (m) before we rewrite it
        if (lane < 4) *(float4*)&red[w * 16 + e4 * 4] = pacc;
        if (lane == 0) rs[w] = lsum;
        __syncthreads();
        if (t < 16) {
            float s = 0.f;
#pragma unroll
            for (int q = 0; q < WAVES; ++q) s += red[q * 16 + t];
            float L = 0.f;
#pragma unroll
            for (int q = 0; q < WAVES; ++q) L += rs[q];
            sv[t] = s / (L * 0.25f);        // L*0.25 = true sum of softmax weights
        }
        __syncthreads();

        // squash -> new outv
        float sq = 0.f;
#pragma unroll
        for (int e = 0; e < 16; ++e) { const float vv = sv[e]; sq += vv * vv; }
        const float scale = sqrtf(sq) / (1.0f + sq);
        outv.x = sv[e4 * 4 + 0] * scale;
        outv.y = sv[e4 * 4 + 1] * scale;
        outv.z = sv[e4 * 4 + 2] * scale;
        outv.w = sv[e4 * 4 + 3] * scale;
    }

    // ---- write out[o, b, 0, 0, :] : threads 0..3 hold e4 = 0..3 ----
    if (t < 4) {
        float4* op = (float4*)(out + (size_t)blockIdx.x * NE);
        op[t] = outv;
    }
}

extern "C" void kernel_launch(void* const* d_in, const int* in_sizes, int n_in,
                              void* d_out, int out_size, void* d_ws, size_t ws_size,
                              hipStream_t stream) {
    const float* x  = (const float*)d_in[0];
    const float* Wt = (const float*)d_in[1];
    float* outp = (float*)d_out;
    caps_routing<<<dim3(NO * BATCH), dim3(THREADS), 0, stream>>>(x, Wt, outp);
}